// Round 8
// baseline (2368.456 us; speedup 1.0000x reference)
//
#include <hip/hip_runtime.h>

#define N_ROWS 65536
#define K_CODES 8192
#define DIM 256
#define CAP 56

// d_out layout (floats): [quantized_st 65536*256][loss 1][indices 65536]
#define LOSS_OFF (N_ROWS * DIM)
#define IDX_OFF (LOSS_OFF + 1)
// scratch inside d_out's quantized region (consumed before gather overwrites):
#define OUT_WBF_U16 0              // W fragments: 8192*256 u16  (4 MB)
#define OUT_ZBF_U16 2097152        // z fragments: 65536*256 u16 (32 MB)
#define OUT_CAND_F 9437184         // cand: 65536*56 uint2 (29.36 MB); ends exactly at 16777216

// d_ws layout (4-byte units), ~1.85 MB total
#define WS_LOSS 0
#define WS_ZNORM 64
#define WS_WNORM (WS_ZNORM + N_ROWS)
#define WS_MARGIN (WS_WNORM + K_CODES)
#define WS_CUT0 (WS_MARGIN + N_ROWS)
#define WS_CNT (WS_CUT0 + N_ROWS)       // uint
#define WS_OVF (WS_CNT + N_ROWS)        // uint counter
#define WS_OVFLIST (WS_OVF + 1)         // uint, up to N_ROWS
#define WS_SLOT (((WS_OVFLIST + N_ROWS) + 1) & ~1)  // u64 per row (8B aligned), 2*N_ROWS u32

typedef __bf16 bf16x8 __attribute__((ext_vector_type(8)));
typedef float f32x4 __attribute__((ext_vector_type(4)));

// ---------- numerics helpers ----------

__device__ __forceinline__ float mul_rn_nofma(float a, float b) {
  float r;
  asm("v_mul_f32 %0, %1, %2" : "=v"(r) : "v"(a), "v"(b));
  return r;
}

// fp32 -> bf16 bits, RNE (error <= 2^-8 rel; the margin derivation assumes this).
__device__ __forceinline__ unsigned int f2bf(float f) {
  unsigned int u = __float_as_uint(f);
  return (u + 0x7FFFu + ((u >> 16) & 1u)) >> 16;
}

// Exact np matmul replica: single ascending-d fmaf chain (bit-proven rounds 1-5).
__device__ float dot_chain(const float* __restrict__ zp, const float* __restrict__ wp) {
  float acc = 0.0f;
#pragma unroll 8
  for (int d4 = 0; d4 < 64; ++d4) {
    const float4 a = *(const float4*)(zp + d4 * 4);
    const float4 b = *(const float4*)(wp + d4 * 4);
    acc = fmaf(a.x, b.x, acc);
    acc = fmaf(a.y, b.y, acc);
    acc = fmaf(a.z, b.z, acc);
    acc = fmaf(a.w, b.w, acc);
  }
  return acc;
}

// ---------- kernels ----------

// FUSED precvt+norms. Norm reduction structure UNCHANGED (bit-exact numpy
// pairwise replica). bf16 copies stored in MFMA-FRAGMENT ORDER (r7-proven):
// element (r, d) -> u16 addr tile*32768 + ks*4096 + sub*512 + lq*128 + lr*8 + j
// where tile=r>>7, sub=((r>>6)&1)*4+((r>>4)&3) (== (r>>4)&7), lr=r&15,
// ks=d>>5, lq=(d>>3)&3, j=d&7.
__global__ void prep_kernel(const float* __restrict__ z, const float* __restrict__ W,
                            float* __restrict__ ws, unsigned short* __restrict__ outu) {
  const int tid = threadIdx.x;
  const int l = tid & 63, w = tid >> 6;
  const int j = l & 7, b = (l >> 3) & 1, rw = l >> 4;
  const int row = blockIdx.x * 16 + w * 4 + rw;  // 0 .. 73727
  const bool isz = (row < N_ROWS);
  const int rr = isz ? row : (row - N_ROWS);
  const float* src = (isz ? z : W) + (size_t)rr * DIM + b * 128;
  unsigned short* fbp = outu + (isz ? OUT_ZBF_U16 : OUT_WBF_U16);
  const int tile = rr >> 7;
  const int sub = ((rr >> 6) & 1) * 4 + ((rr >> 4) & 3);
  const unsigned int basea =
      (unsigned int)tile * 32768u + (unsigned int)sub * 512u + (unsigned int)(rr & 15) * 8u + j;

  float a0 = src[j];
  {
    const int ksq = b * 16;  // t = 0
    fbp[basea + (ksq >> 2) * 4096 + (ksq & 3) * 128] = (unsigned short)f2bf(a0);
  }
  float r = mul_rn_nofma(a0, a0);
  float s = fabsf(a0);
  for (int i = 8; i < 128; i += 8) {
    const float v = src[i + j];
    const int ksq = b * 16 + (i >> 3);
    fbp[basea + (ksq >> 2) * 4096 + (ksq & 3) * 128] = (unsigned short)f2bf(v);
    r = r + mul_rn_nofma(v, v);
    s = s + fabsf(v);
  }
  // exact numpy pairwise tree: ((r0+r1)+(r2+r3))+((r4+r5)+(r6+r7)), then blk0+blk1
  r = r + __shfl_xor(r, 1, 64);
  r = r + __shfl_xor(r, 2, 64);
  r = r + __shfl_xor(r, 4, 64);
  r = r + __shfl_xor(r, 8, 64);
  s = s + __shfl_xor(s, 1, 64);
  s = s + __shfl_xor(s, 2, 64);
  s = s + __shfl_xor(s, 4, 64);
  s = s + __shfl_xor(s, 8, 64);
  if ((l & 15) == 0) {
    if (isz) {
      ws[WS_ZNORM + row] = r;
      const float margin = 2.0e-6f * s + 4.0e-5f;
      ws[WS_MARGIN + row] = margin;
      ws[WS_CUT0 + row] = 3.10f * sqrtf(r) * 7.0467e-5f - margin;
      ((unsigned int*)ws)[WS_CNT + row] = 0u;
    } else {
      ws[WS_WNORM + (row - N_ROWS)] = r;
    }
  }
  if (blockIdx.x == 0 && tid == 0) {
    ws[WS_LOSS] = 0.0f;
    ((unsigned int*)ws)[WS_OVF] = 0u;
  }
}

// bf16 MFMA screen GEMM - NO LDS, NO BARRIERS, 128x128 WAVE TILE.
// Theory (r7 post-mortem): r7's 64x64 wave tile moves 512 B of operand per
// MFMA; per-CU load demand ~190 B/cyc vs ~56 B/cyc L2 + L1 assist -> the
// operand-load pipe, not MFMA and not sync, is the 22.6%-util binding
// constraint (explains the whole r0-r6 ~520-580us plateau). Fix: QUADRUPLE
// the register tile -> 128x128 per wave (acc[8][8] = 256 AGPR, unified file),
// 16 loads per 64 MFMA = 250 B/MFMA, and the block's 2x A / 2x B redundancy
// becomes L1-resident (32 KB unique per block-step). Block = 4 waves (2x2) =
// 256x256 tile; grid (32, 256). ~356 regs/wave -> ~5 waves/SIMD available.
// Per-output MFMA order unchanged (ks ascending, identical fragment values)
// -> acc bits identical -> candidate set & margin proof intact.
__global__ __launch_bounds__(256, 2) void gemm_screen_kernel(
    const unsigned short* __restrict__ zfrag, const unsigned short* __restrict__ wfrag,
    float* __restrict__ ws, uint2* __restrict__ candp) {
  const int tid = threadIdx.x;
  const int w = tid >> 6, l = tid & 63;
  const int lr = l & 15, lq = l >> 4;
  const int wr = (w >> 1) * 128, wc = (w & 1) * 128;
  const int rowBase = blockIdx.y * 256, colBase = blockIdx.x * 256;
  unsigned int* cntp = (unsigned int*)ws + WS_CNT;

  // fragment pointers, 16B units: flat = tile*4096 + ks*512 + sub*64 + l
  const bf16x8* za =
      (const bf16x8*)zfrag + ((size_t)(blockIdx.y * 2 + (w >> 1))) * 4096 + l;
  const bf16x8* wa =
      (const bf16x8*)wfrag + ((size_t)(blockIdx.x * 2 + (w & 1))) * 4096 + l;

  f32x4 acc[8][8];
#pragma unroll
  for (int mi = 0; mi < 8; ++mi)
#pragma unroll
    for (int ni = 0; ni < 8; ++ni) acc[mi][ni] = (f32x4){0.f, 0.f, 0.f, 0.f};

#pragma unroll
  for (int ks = 0; ks < 8; ++ks) {
    bf16x8 af[8], bfr[8];
#pragma unroll
    for (int mi = 0; mi < 8; ++mi) af[mi] = za[ks * 512 + mi * 64];
#pragma unroll
    for (int ni = 0; ni < 8; ++ni) bfr[ni] = wa[ks * 512 + ni * 64];
#pragma unroll
    for (int mi = 0; mi < 8; ++mi)
#pragma unroll
      for (int ni = 0; ni < 8; ++ni)
        acc[mi][ni] =
            __builtin_amdgcn_mfma_f32_16x16x32_bf16(af[mi], bfr[ni], acc[mi][ni], 0, 0, 0);
  }

  // Append-only epilogue (r5-proven): C/D layout col = lane&15,
  // row = (lane>>4)*4 + reg; cuts read as float4 straight from ws.
#pragma unroll
  for (int mi = 0; mi < 8; ++mi) {
    const float4 cutv = *(const float4*)(ws + WS_CUT0 + rowBase + wr + mi * 16 + lq * 4);
    const float cuta[4] = {cutv.x, cutv.y, cutv.z, cutv.w};
#pragma unroll
    for (int r = 0; r < 4; ++r) {
      const int lrow = wr + mi * 16 + lq * 4 + r;
      const float cut = cuta[r];
#pragma unroll
      for (int ni = 0; ni < 8; ++ni) {
        if (acc[mi][ni][r] >= cut) {
          const int grow = rowBase + lrow;
          const int gcol = colBase + wc + ni * 16 + lr;
          const unsigned int pos = atomicAdd(&cntp[grow], 1u);
          if (pos < CAP) {
            uint2 e;
            e.x = __float_as_uint(acc[mi][ni][r]);
            e.y = (unsigned int)gcol;
            candp[(size_t)grow * CAP + pos] = e;
          }
        }
      }
    }
  }
}

// One WAVE per row. Lanes 0..cv-1 load candidates coalesced; shuffle-reduce
// candmax; rigor gate unchanged. Survivors run the exact np dot_chain in
// parallel lanes; argmin via packed (dist_bits<<32 | k) key (dist ~ 256 > 0 ->
// uint order = float order; ties -> lowest k = np.argmin). Fallback rows get a
// -1 sentinel index; gather_loss resolves them from the u64 slots.
__global__ void recheck_kernel(const float* __restrict__ z, const float* __restrict__ W,
                               float* __restrict__ ws, const uint2* __restrict__ candp,
                               float* __restrict__ out) {
  const int lane = threadIdx.x & 63;
  const int row = blockIdx.x * 4 + (threadIdx.x >> 6);
  const unsigned int cv = ((const unsigned int*)ws)[WS_CNT + row];
  const float margin = ws[WS_MARGIN + row];
  const float cut0 = ws[WS_CUT0 + row];
  bool fb = (cv == 0u) || (cv > CAP);
  uint2 e;
  e.x = 0u; e.y = 0u;
  float av = -3.4e38f;
  if (!fb && lane < (int)cv) {
    e = candp[(size_t)row * CAP + lane];
    av = __uint_as_float(e.x);
  }
  float candmax = av;
#pragma unroll
  for (int s = 1; s < 64; s <<= 1) candmax = fmaxf(candmax, __shfl_xor(candmax, s, 64));
  if (!fb && candmax - margin < cut0) fb = true;  // cannot prove superset -> exact scan
  if (fb) {
    if (lane == 0) {
      ((unsigned long long*)((unsigned int*)ws + WS_SLOT))[row] = ~0ull;
      const unsigned int p = atomicAdd(&((unsigned int*)ws)[WS_OVF], 1u);
      ((unsigned int*)ws)[WS_OVFLIST + p] = (unsigned int)row;
      out[IDX_OFF + row] = -1.0f;  // sentinel: resolved by gather_loss
    }
    return;
  }
  const float fcut = candmax - margin;
  unsigned long long key = ~0ull;
  if (lane < (int)cv && av >= fcut) {  // below final cut: cannot be argmin
    const int k = (int)e.y;
    const float zn = ws[WS_ZNORM + row];
    const float m = dot_chain(z + (size_t)row * DIM, W + (size_t)k * DIM);
    const float dist = (zn + ws[WS_WNORM + k]) - 2.0f * m;
    key = ((unsigned long long)__float_as_uint(dist) << 32) | (unsigned int)k;
  }
#pragma unroll
  for (int s = 1; s < 64; s <<= 1) {
    const unsigned long long o = (unsigned long long)__shfl_xor((long long)key, s, 64);
    key = (o < key) ? o : key;
  }
  if (lane == 0) out[IDX_OFF + row] = (float)(unsigned int)(key & 0xffffffffull);
}

// Grid-parallel exact fallback: work item = (queued row, 256-code chunk). Each
// thread one code -> exact np dist; block-reduce min; u64 atomicMin combine.
__global__ void fallback_compute(const float* __restrict__ z, const float* __restrict__ W,
                                 float* __restrict__ ws) {
  __shared__ unsigned long long part[4];
  const unsigned int n = ((const unsigned int*)ws)[WS_OVF];
  unsigned long long* slots = (unsigned long long*)((unsigned int*)ws + WS_SLOT);
  const unsigned int total = n * 32u;
  for (unsigned int item = blockIdx.x; item < total; item += gridDim.x) {
    const int row = (int)((const unsigned int*)ws)[WS_OVFLIST + (item >> 5)];
    const int k = (int)(item & 31u) * 256 + threadIdx.x;
    const float zn = ws[WS_ZNORM + row];
    const float m = dot_chain(z + (size_t)row * DIM, W + (size_t)k * DIM);
    const float dist = (zn + ws[WS_WNORM + k]) - 2.0f * m;
    unsigned long long key =
        ((unsigned long long)__float_as_uint(dist) << 32) | (unsigned int)k;
#pragma unroll
    for (int s = 1; s < 64; s <<= 1) {
      const unsigned long long o = __shfl_xor((long long)key, s, 64);
      key = (o < key) ? o : key;
    }
    if ((threadIdx.x & 63) == 0) part[threadIdx.x >> 6] = key;
    __syncthreads();
    if (threadIdx.x == 0) {
      unsigned long long b = part[0];
      b = (part[1] < b) ? part[1] : b;
      b = (part[2] < b) ? part[2] : b;
      b = (part[3] < b) ? part[3] : b;
      atomicMin(&slots[row], b);
    }
    __syncthreads();
  }
}

// 64 rows/block: gather W[idx], quantized_st = z + (q - z), loss partial sums.
// Rows with the -1 sentinel read their exact-fallback result from the u64 slot.
__global__ void gather_loss_kernel(const float* __restrict__ z, const float* __restrict__ W,
                                   float* __restrict__ out, float* __restrict__ ws) {
  const int tid = threadIdx.x;
  const int rowBase = blockIdx.x * 64;
  float lsum = 0.0f;
  for (int p = 0; p < 16; ++p) {
    const int row = rowBase + p * 4 + (tid >> 6);
    const int c4 = tid & 63;
    int idx = (int)out[IDX_OFF + row];
    if (idx < 0) {
      const unsigned long long key =
          ((const unsigned long long*)((const unsigned int*)ws + WS_SLOT))[row];
      idx = (int)(unsigned int)(key & 0xffffffffull);
      out[IDX_OFF + row] = (float)idx;  // all 64 threads write same value: benign
    }
    const float4 zv = *(const float4*)(z + (size_t)row * DIM + c4 * 4);
    const float4 qv = *(const float4*)(W + (size_t)idx * DIM + c4 * 4);
    float4 t, o;
    t.x = qv.x - zv.x; t.y = qv.y - zv.y; t.z = qv.z - zv.z; t.w = qv.w - zv.w;
    o.x = zv.x + t.x;  o.y = zv.y + t.y;  o.z = zv.z + t.z;  o.w = zv.w + t.w;
    *(float4*)(out + (size_t)row * DIM + c4 * 4) = o;
    lsum += t.x * t.x + t.y * t.y + t.z * t.z + t.w * t.w;
  }
#pragma unroll
  for (int m = 1; m < 64; m <<= 1) lsum += __shfl_xor(lsum, m, 64);
  __shared__ float part[4];
  if ((tid & 63) == 0) part[tid >> 6] = lsum;
  __syncthreads();
  if (tid == 0) atomicAdd(&ws[WS_LOSS], (part[0] + part[1]) + (part[2] + part[3]));
}

__global__ void finalize_kernel(const float* __restrict__ ws, float* __restrict__ out) {
  if (threadIdx.x == 0 && blockIdx.x == 0) {
    const float mean = ws[WS_LOSS] / (float)(N_ROWS * DIM);
    out[LOSS_OFF] = mean + 0.25f * mean;
  }
}

extern "C" void kernel_launch(void* const* d_in, const int* in_sizes, int n_in,
                              void* d_out, int out_size, void* d_ws, size_t ws_size,
                              hipStream_t stream) {
  (void)in_sizes; (void)n_in; (void)out_size; (void)ws_size;
  const float* z = (const float*)d_in[0];
  const float* W = (const float*)d_in[1];
  float* out = (float*)d_out;
  float* ws = (float*)d_ws;
  unsigned short* outu = (unsigned short*)d_out;
  const unsigned short* wfrag = outu + OUT_WBF_U16;
  const unsigned short* zfrag = outu + OUT_ZBF_U16;
  uint2* candp = (uint2*)((float*)d_out + OUT_CAND_F);

  hipLaunchKernelGGL(prep_kernel, dim3((N_ROWS + K_CODES) / 16), dim3(256), 0, stream,
                     z, W, ws, outu);
  hipLaunchKernelGGL(gemm_screen_kernel, dim3(K_CODES / 256, N_ROWS / 256), dim3(256),
                     0, stream, zfrag, wfrag, ws, candp);
  hipLaunchKernelGGL(recheck_kernel, dim3(N_ROWS / 4), dim3(256), 0, stream,
                     z, W, ws, candp, out);
  hipLaunchKernelGGL(fallback_compute, dim3(2048), dim3(256), 0, stream, z, W, ws);
  hipLaunchKernelGGL(gather_loss_kernel, dim3(N_ROWS / 64), dim3(256), 0, stream,
                     z, W, out, ws);
  hipLaunchKernelGGL(finalize_kernel, dim3(1), dim3(64), 0, stream, ws, out);
}

// Round 9
// 1037.984 us; speedup vs baseline: 2.2818x; 2.2818x over previous
//
#include <hip/hip_runtime.h>

#define N_ROWS 65536
#define K_CODES 8192
#define DIM 256
#define CAP 56

// d_out layout (floats): [quantized_st 65536*256][loss 1][indices 65536]
#define LOSS_OFF (N_ROWS * DIM)
#define IDX_OFF (LOSS_OFF + 1)
// scratch inside d_out's quantized region (consumed before gather overwrites):
#define OUT_WBF_U16 0              // W fragments: 8192*256 u16  (4 MB)
#define OUT_ZBF_U16 2097152        // z fragments: 65536*256 u16 (32 MB)
#define OUT_CAND_F 9437184         // cand: 65536*56 uint2 (29.36 MB); ends exactly at 16777216

// d_ws layout (4-byte units), ~1.85 MB total
#define WS_LOSS 0
#define WS_ZNORM 64
#define WS_WNORM (WS_ZNORM + N_ROWS)
#define WS_MARGIN (WS_WNORM + K_CODES)
#define WS_CUT0 (WS_MARGIN + N_ROWS)
#define WS_CNT (WS_CUT0 + N_ROWS)       // uint
#define WS_OVF (WS_CNT + N_ROWS)        // uint counter
#define WS_OVFLIST (WS_OVF + 1)         // uint, up to N_ROWS
#define WS_SLOT (((WS_OVFLIST + N_ROWS) + 1) & ~1)  // u64 per row (8B aligned), 2*N_ROWS u32

typedef __bf16 bf16x8 __attribute__((ext_vector_type(8)));
typedef float f32x4 __attribute__((ext_vector_type(4)));

// ---------- numerics helpers ----------

__device__ __forceinline__ float mul_rn_nofma(float a, float b) {
  float r;
  asm("v_mul_f32 %0, %1, %2" : "=v"(r) : "v"(a), "v"(b));
  return r;
}

// fp32 -> bf16 bits, RNE (error <= 2^-8 rel; the margin derivation assumes this).
__device__ __forceinline__ unsigned int f2bf(float f) {
  unsigned int u = __float_as_uint(f);
  return (u + 0x7FFFu + ((u >> 16) & 1u)) >> 16;
}

// Exact np matmul replica: single ascending-d fmaf chain (bit-proven rounds 1-5).
__device__ float dot_chain(const float* __restrict__ zp, const float* __restrict__ wp) {
  float acc = 0.0f;
#pragma unroll 8
  for (int d4 = 0; d4 < 64; ++d4) {
    const float4 a = *(const float4*)(zp + d4 * 4);
    const float4 b = *(const float4*)(wp + d4 * 4);
    acc = fmaf(a.x, b.x, acc);
    acc = fmaf(a.y, b.y, acc);
    acc = fmaf(a.z, b.z, acc);
    acc = fmaf(a.w, b.w, acc);
  }
  return acc;
}

// global -> LDS 16B DMA (wave-uniform LDS base + lane*16).
__device__ __forceinline__ void glds16(const void* g, void* l) {
  __builtin_amdgcn_global_load_lds(
      (const __attribute__((address_space(1))) void*)(unsigned long long)(size_t)g,
      (__attribute__((address_space(3))) void*)(unsigned int)(size_t)l, 16, 0, 0);
}

// ---------- kernels ----------

// FUSED precvt+norms. Norm reduction structure UNCHANGED (bit-exact numpy
// pairwise replica). bf16 copies stored in MFMA-FRAGMENT ORDER (r7-proven):
// element (r, d) -> u16 addr tile*32768 + ks*4096 + sub*512 + lq*128 + lr*8 + j
// where tile=r>>7, sub=(r>>4)&7, lr=r&15, ks=d>>5, lq=(d>>3)&3, j=d&7.
__global__ void prep_kernel(const float* __restrict__ z, const float* __restrict__ W,
                            float* __restrict__ ws, unsigned short* __restrict__ outu) {
  const int tid = threadIdx.x;
  const int l = tid & 63, w = tid >> 6;
  const int j = l & 7, b = (l >> 3) & 1, rw = l >> 4;
  const int row = blockIdx.x * 16 + w * 4 + rw;  // 0 .. 73727
  const bool isz = (row < N_ROWS);
  const int rr = isz ? row : (row - N_ROWS);
  const float* src = (isz ? z : W) + (size_t)rr * DIM + b * 128;
  unsigned short* fbp = outu + (isz ? OUT_ZBF_U16 : OUT_WBF_U16);
  const int tile = rr >> 7;
  const int sub = ((rr >> 6) & 1) * 4 + ((rr >> 4) & 3);
  const unsigned int basea =
      (unsigned int)tile * 32768u + (unsigned int)sub * 512u + (unsigned int)(rr & 15) * 8u + j;

  float a0 = src[j];
  {
    const int ksq = b * 16;  // t = 0
    fbp[basea + (ksq >> 2) * 4096 + (ksq & 3) * 128] = (unsigned short)f2bf(a0);
  }
  float r = mul_rn_nofma(a0, a0);
  float s = fabsf(a0);
  for (int i = 8; i < 128; i += 8) {
    const float v = src[i + j];
    const int ksq = b * 16 + (i >> 3);
    fbp[basea + (ksq >> 2) * 4096 + (ksq & 3) * 128] = (unsigned short)f2bf(v);
    r = r + mul_rn_nofma(v, v);
    s = s + fabsf(v);
  }
  // exact numpy pairwise tree: ((r0+r1)+(r2+r3))+((r4+r5)+(r6+r7)), then blk0+blk1
  r = r + __shfl_xor(r, 1, 64);
  r = r + __shfl_xor(r, 2, 64);
  r = r + __shfl_xor(r, 4, 64);
  r = r + __shfl_xor(r, 8, 64);
  s = s + __shfl_xor(s, 1, 64);
  s = s + __shfl_xor(s, 2, 64);
  s = s + __shfl_xor(s, 4, 64);
  s = s + __shfl_xor(s, 8, 64);
  if ((l & 15) == 0) {
    if (isz) {
      ws[WS_ZNORM + row] = r;
      const float margin = 2.0e-6f * s + 4.0e-5f;
      ws[WS_MARGIN + row] = margin;
      ws[WS_CUT0 + row] = 3.10f * sqrtf(r) * 7.0467e-5f - margin;
      ((unsigned int*)ws)[WS_CNT + row] = 0u;
    } else {
      ws[WS_WNORM + (row - N_ROWS)] = r;
    }
  }
  if (blockIdx.x == 0 && tid == 0) {
    ws[WS_LOSS] = 0.0f;
    ((unsigned int*)ws)[WS_OVF] = 0u;
  }
}

// bf16 MFMA screen GEMM - TWO-PIPE SPLIT, 64x128 wave tile.
// Theory (r7/r8 post-mortems): r7 saturated the per-CU vector-load path
// (~64 B/cyc); r8's bigger register tile spilled (330 regs > 256 cap, 7.8 GB
// scratch). Fix within the register budget: split operand traffic across
// pipes. B-tile (128 W-cols = ONE fragment tile = 64 KB, contiguous) is
// LDS-resident per block, staged once via glds16 + ONE __syncthreads; A-frags
// load direct global->VGPR (r7-proven). Each wave sweeps 4 independent 64-row
// strips (block covers 1024 rows), zero barriers in steady state. Per ks-step:
// 4 A-loads (vector pipe) + 8 ds_read_b128 (LDS pipe, lanes consecutive 16 B =
// conflict-free) + 32 MFMA. acc[4][8]=128 regs + 48 frag ~= 200 < 256: NO
// spill (tripwire: WRITE_SIZE must stay ~88 MB). Vector pipe ~15 B/cyc, LDS
// ~28 B/cyc at 250 us -> both far under peak; MFMA floor 132 us reachable.
// B staged verbatim; per-output MFMA order unchanged (ks ascending, same
// fragment values) -> acc bits identical -> candidate set & proof intact.
__global__ __launch_bounds__(256, 2) void gemm_screen_kernel(
    const unsigned short* __restrict__ zfrag, const unsigned short* __restrict__ wfrag,
    float* __restrict__ ws, uint2* __restrict__ candp) {
  __shared__ __align__(16) unsigned short Bs[32768];  // 64 KB = one W fragment tile

  const int tid = threadIdx.x;
  const int w = tid >> 6, l = tid & 63;
  const int lr = l & 15, lq = l >> 4;
  const int colBase = blockIdx.x * 128;  // = fragment tile blockIdx.x
  unsigned int* cntp = (unsigned int*)ws + WS_CNT;

  // ---- stage B tile (4096 x 16B chunks, contiguous): wave w does 16 wave-ops
  {
    const bf16x8* wsrc = (const bf16x8*)wfrag + (size_t)blockIdx.x * 4096;
#pragma unroll
    for (int t = 0; t < 16; ++t)
      glds16(wsrc + w * 1024 + t * 64 + l, (char*)Bs + (w * 1024 + t * 64) * 16);
  }
  __syncthreads();  // B resident; the ONLY barrier

  const bf16x8* bsp = (const bf16x8*)Bs;

  for (int s = 0; s < 4; ++s) {
    const int st = s * 4 + w;                       // strip 0..15 (64 rows each)
    const int rtile = blockIdx.y * 8 + (st >> 1);   // z fragment tile
    const int half = st & 1;                        // 64-row half of the tile
    const bf16x8* za = (const bf16x8*)zfrag + (size_t)rtile * 4096 + half * 256 + l;
    const int rowBase = blockIdx.y * 1024 + st * 64;

    f32x4 acc[4][8];
#pragma unroll
    for (int mi = 0; mi < 4; ++mi)
#pragma unroll
      for (int ni = 0; ni < 8; ++ni) acc[mi][ni] = (f32x4){0.f, 0.f, 0.f, 0.f};

#pragma unroll
    for (int ks = 0; ks < 8; ++ks) {
      bf16x8 af[4], bfr[8];
#pragma unroll
      for (int mi = 0; mi < 4; ++mi) af[mi] = za[ks * 512 + mi * 64];
#pragma unroll
      for (int ni = 0; ni < 8; ++ni) bfr[ni] = bsp[ks * 512 + ni * 64 + l];
#pragma unroll
      for (int mi = 0; mi < 4; ++mi)
#pragma unroll
        for (int ni = 0; ni < 8; ++ni)
          acc[mi][ni] =
              __builtin_amdgcn_mfma_f32_16x16x32_bf16(af[mi], bfr[ni], acc[mi][ni], 0, 0, 0);
    }

    // Append-only epilogue (r5-proven): C/D layout col = lane&15,
    // row = (lane>>4)*4 + reg; cuts read as float4 straight from ws.
#pragma unroll
    for (int mi = 0; mi < 4; ++mi) {
      const float4 cutv = *(const float4*)(ws + WS_CUT0 + rowBase + mi * 16 + lq * 4);
      const float cuta[4] = {cutv.x, cutv.y, cutv.z, cutv.w};
#pragma unroll
      for (int r = 0; r < 4; ++r) {
        const int grow = rowBase + mi * 16 + lq * 4 + r;
        const float cut = cuta[r];
#pragma unroll
        for (int ni = 0; ni < 8; ++ni) {
          if (acc[mi][ni][r] >= cut) {
            const int gcol = colBase + ni * 16 + lr;
            const unsigned int pos = atomicAdd(&cntp[grow], 1u);
            if (pos < CAP) {
              uint2 e;
              e.x = __float_as_uint(acc[mi][ni][r]);
              e.y = (unsigned int)gcol;
              candp[(size_t)grow * CAP + pos] = e;
            }
          }
        }
      }
    }
  }
}

// One WAVE per row. Lanes 0..cv-1 load candidates coalesced; shuffle-reduce
// candmax; rigor gate unchanged. Survivors run the exact np dot_chain in
// parallel lanes; argmin via packed (dist_bits<<32 | k) key (dist ~ 256 > 0 ->
// uint order = float order; ties -> lowest k = np.argmin). Fallback rows get a
// -1 sentinel index; gather_loss resolves them from the u64 slots.
__global__ void recheck_kernel(const float* __restrict__ z, const float* __restrict__ W,
                               float* __restrict__ ws, const uint2* __restrict__ candp,
                               float* __restrict__ out) {
  const int lane = threadIdx.x & 63;
  const int row = blockIdx.x * 4 + (threadIdx.x >> 6);
  const unsigned int cv = ((const unsigned int*)ws)[WS_CNT + row];
  const float margin = ws[WS_MARGIN + row];
  const float cut0 = ws[WS_CUT0 + row];
  bool fb = (cv == 0u) || (cv > CAP);
  uint2 e;
  e.x = 0u; e.y = 0u;
  float av = -3.4e38f;
  if (!fb && lane < (int)cv) {
    e = candp[(size_t)row * CAP + lane];
    av = __uint_as_float(e.x);
  }
  float candmax = av;
#pragma unroll
  for (int s = 1; s < 64; s <<= 1) candmax = fmaxf(candmax, __shfl_xor(candmax, s, 64));
  if (!fb && candmax - margin < cut0) fb = true;  // cannot prove superset -> exact scan
  if (fb) {
    if (lane == 0) {
      ((unsigned long long*)((unsigned int*)ws + WS_SLOT))[row] = ~0ull;
      const unsigned int p = atomicAdd(&((unsigned int*)ws)[WS_OVF], 1u);
      ((unsigned int*)ws)[WS_OVFLIST + p] = (unsigned int)row;
      out[IDX_OFF + row] = -1.0f;  // sentinel: resolved by gather_loss
    }
    return;
  }
  const float fcut = candmax - margin;
  unsigned long long key = ~0ull;
  if (lane < (int)cv && av >= fcut) {  // below final cut: cannot be argmin
    const int k = (int)e.y;
    const float zn = ws[WS_ZNORM + row];
    const float m = dot_chain(z + (size_t)row * DIM, W + (size_t)k * DIM);
    const float dist = (zn + ws[WS_WNORM + k]) - 2.0f * m;
    key = ((unsigned long long)__float_as_uint(dist) << 32) | (unsigned int)k;
  }
#pragma unroll
  for (int s = 1; s < 64; s <<= 1) {
    const unsigned long long o = (unsigned long long)__shfl_xor((long long)key, s, 64);
    key = (o < key) ? o : key;
  }
  if (lane == 0) out[IDX_OFF + row] = (float)(unsigned int)(key & 0xffffffffull);
}

// Grid-parallel exact fallback: work item = (queued row, 256-code chunk). Each
// thread one code -> exact np dist; block-reduce min; u64 atomicMin combine.
__global__ void fallback_compute(const float* __restrict__ z, const float* __restrict__ W,
                                 float* __restrict__ ws) {
  __shared__ unsigned long long part[4];
  const unsigned int n = ((const unsigned int*)ws)[WS_OVF];
  unsigned long long* slots = (unsigned long long*)((unsigned int*)ws + WS_SLOT);
  const unsigned int total = n * 32u;
  for (unsigned int item = blockIdx.x; item < total; item += gridDim.x) {
    const int row = (int)((const unsigned int*)ws)[WS_OVFLIST + (item >> 5)];
    const int k = (int)(item & 31u) * 256 + threadIdx.x;
    const float zn = ws[WS_ZNORM + row];
    const float m = dot_chain(z + (size_t)row * DIM, W + (size_t)k * DIM);
    const float dist = (zn + ws[WS_WNORM + k]) - 2.0f * m;
    unsigned long long key =
        ((unsigned long long)__float_as_uint(dist) << 32) | (unsigned int)k;
#pragma unroll
    for (int s = 1; s < 64; s <<= 1) {
      const unsigned long long o = __shfl_xor((long long)key, s, 64);
      key = (o < key) ? o : key;
    }
    if ((threadIdx.x & 63) == 0) part[threadIdx.x >> 6] = key;
    __syncthreads();
    if (threadIdx.x == 0) {
      unsigned long long b = part[0];
      b = (part[1] < b) ? part[1] : b;
      b = (part[2] < b) ? part[2] : b;
      b = (part[3] < b) ? part[3] : b;
      atomicMin(&slots[row], b);
    }
    __syncthreads();
  }
}

// 64 rows/block: gather W[idx], quantized_st = z + (q - z), loss partial sums.
// Rows with the -1 sentinel read their exact-fallback result from the u64 slot.
__global__ void gather_loss_kernel(const float* __restrict__ z, const float* __restrict__ W,
                                   float* __restrict__ out, float* __restrict__ ws) {
  const int tid = threadIdx.x;
  const int rowBase = blockIdx.x * 64;
  float lsum = 0.0f;
  for (int p = 0; p < 16; ++p) {
    const int row = rowBase + p * 4 + (tid >> 6);
    const int c4 = tid & 63;
    int idx = (int)out[IDX_OFF + row];
    if (idx < 0) {
      const unsigned long long key =
          ((const unsigned long long*)((const unsigned int*)ws + WS_SLOT))[row];
      idx = (int)(unsigned int)(key & 0xffffffffull);
      out[IDX_OFF + row] = (float)idx;  // all 64 threads write same value: benign
    }
    const float4 zv = *(const float4*)(z + (size_t)row * DIM + c4 * 4);
    const float4 qv = *(const float4*)(W + (size_t)idx * DIM + c4 * 4);
    float4 t, o;
    t.x = qv.x - zv.x; t.y = qv.y - zv.y; t.z = qv.z - zv.z; t.w = qv.w - zv.w;
    o.x = zv.x + t.x;  o.y = zv.y + t.y;  o.z = zv.z + t.z;  o.w = zv.w + t.w;
    *(float4*)(out + (size_t)row * DIM + c4 * 4) = o;
    lsum += t.x * t.x + t.y * t.y + t.z * t.z + t.w * t.w;
  }
#pragma unroll
  for (int m = 1; m < 64; m <<= 1) lsum += __shfl_xor(lsum, m, 64);
  __shared__ float part[4];
  if ((tid & 63) == 0) part[tid >> 6] = lsum;
  __syncthreads();
  if (tid == 0) atomicAdd(&ws[WS_LOSS], (part[0] + part[1]) + (part[2] + part[3]));
}

__global__ void finalize_kernel(const float* __restrict__ ws, float* __restrict__ out) {
  if (threadIdx.x == 0 && blockIdx.x == 0) {
    const float mean = ws[WS_LOSS] / (float)(N_ROWS * DIM);
    out[LOSS_OFF] = mean + 0.25f * mean;
  }
}

extern "C" void kernel_launch(void* const* d_in, const int* in_sizes, int n_in,
                              void* d_out, int out_size, void* d_ws, size_t ws_size,
                              hipStream_t stream) {
  (void)in_sizes; (void)n_in; (void)out_size; (void)ws_size;
  const float* z = (const float*)d_in[0];
  const float* W = (const float*)d_in[1];
  float* out = (float*)d_out;
  float* ws = (float*)d_ws;
  unsigned short* outu = (unsigned short*)d_out;
  const unsigned short* wfrag = outu + OUT_WBF_U16;
  const unsigned short* zfrag = outu + OUT_ZBF_U16;
  uint2* candp = (uint2*)((float*)d_out + OUT_CAND_F);

  hipLaunchKernelGGL(prep_kernel, dim3((N_ROWS + K_CODES) / 16), dim3(256), 0, stream,
                     z, W, ws, outu);
  // 64 col-tiles x 64 row-groups of 1024 rows; x-major keeps z groups L2-hot.
  hipLaunchKernelGGL(gemm_screen_kernel, dim3(K_CODES / 128, N_ROWS / 1024), dim3(256),
                     0, stream, zfrag, wfrag, ws, candp);
  hipLaunchKernelGGL(recheck_kernel, dim3(N_ROWS / 4), dim3(256), 0, stream,
                     z, W, ws, candp, out);
  hipLaunchKernelGGL(fallback_compute, dim3(2048), dim3(256), 0, stream, z, W, ws);
  hipLaunchKernelGGL(gather_loss_kernel, dim3(N_ROWS / 64), dim3(256), 0, stream,
                     z, W, out, ws);
  hipLaunchKernelGGL(finalize_kernel, dim3(1), dim3(64), 0, stream, ws, out);
}

// Round 10
// 929.351 us; speedup vs baseline: 2.5485x; 1.1169x over previous
//
#include <hip/hip_runtime.h>

#define N_ROWS 65536
#define K_CODES 8192
#define DIM 256
#define CAP 56

// d_out layout (floats): [quantized_st 65536*256][loss 1][indices 65536]
#define LOSS_OFF (N_ROWS * DIM)
#define IDX_OFF (LOSS_OFF + 1)
// scratch inside d_out's quantized region (consumed before gather overwrites):
#define OUT_WBF_U16 0              // W fragments: 8192*256 u16  (4 MB)
#define OUT_ZBF_U16 2097152        // z fragments: 65536*256 u16 (32 MB)
#define OUT_CAND_F 9437184         // cand: 65536*56 uint2 (29.36 MB); ends exactly at 16777216

// d_ws layout (4-byte units), ~1.85 MB total
#define WS_LOSS 0
#define WS_ZNORM 64
#define WS_WNORM (WS_ZNORM + N_ROWS)
#define WS_MARGIN (WS_WNORM + K_CODES)
#define WS_CUT0 (WS_MARGIN + N_ROWS)
#define WS_CNT (WS_CUT0 + N_ROWS)       // uint
#define WS_OVF (WS_CNT + N_ROWS)        // uint counter
#define WS_OVFLIST (WS_OVF + 1)         // uint, up to N_ROWS
#define WS_SLOT (((WS_OVFLIST + N_ROWS) + 1) & ~1)  // u64 per row (8B aligned), 2*N_ROWS u32

typedef __bf16 bf16x8 __attribute__((ext_vector_type(8)));
typedef float f32x4 __attribute__((ext_vector_type(4)));

// ---------- numerics helpers ----------

__device__ __forceinline__ float mul_rn_nofma(float a, float b) {
  float r;
  asm("v_mul_f32 %0, %1, %2" : "=v"(r) : "v"(a), "v"(b));
  return r;
}

// fp32 -> bf16 bits, RNE (error <= 2^-8 rel; the margin derivation assumes this).
__device__ __forceinline__ unsigned int f2bf(float f) {
  unsigned int u = __float_as_uint(f);
  return (u + 0x7FFFu + ((u >> 16) & 1u)) >> 16;
}

// Exact np matmul replica: single ascending-d fmaf chain (bit-proven rounds 1-5).
__device__ float dot_chain(const float* __restrict__ zp, const float* __restrict__ wp) {
  float acc = 0.0f;
#pragma unroll 8
  for (int d4 = 0; d4 < 64; ++d4) {
    const float4 a = *(const float4*)(zp + d4 * 4);
    const float4 b = *(const float4*)(wp + d4 * 4);
    acc = fmaf(a.x, b.x, acc);
    acc = fmaf(a.y, b.y, acc);
    acc = fmaf(a.z, b.z, acc);
    acc = fmaf(a.w, b.w, acc);
  }
  return acc;
}

// ---------- kernels ----------

// FUSED precvt+norms. Norm reduction structure UNCHANGED (bit-exact numpy
// pairwise replica). bf16 copies stored in MFMA-FRAGMENT ORDER (r7-proven):
// element (r, d) -> u16 addr tile*32768 + ks*4096 + sub*512 + lq*128 + lr*8 + j
// where tile=r>>7, sub=(r>>4)&7, lr=r&15, ks=d>>5, lq=(d>>3)&3, j=d&7.
__global__ void prep_kernel(const float* __restrict__ z, const float* __restrict__ W,
                            float* __restrict__ ws, unsigned short* __restrict__ outu) {
  const int tid = threadIdx.x;
  const int l = tid & 63, w = tid >> 6;
  const int j = l & 7, b = (l >> 3) & 1, rw = l >> 4;
  const int row = blockIdx.x * 16 + w * 4 + rw;  // 0 .. 73727
  const bool isz = (row < N_ROWS);
  const int rr = isz ? row : (row - N_ROWS);
  const float* src = (isz ? z : W) + (size_t)rr * DIM + b * 128;
  unsigned short* fbp = outu + (isz ? OUT_ZBF_U16 : OUT_WBF_U16);
  const int tile = rr >> 7;
  const int sub = ((rr >> 6) & 1) * 4 + ((rr >> 4) & 3);
  const unsigned int basea =
      (unsigned int)tile * 32768u + (unsigned int)sub * 512u + (unsigned int)(rr & 15) * 8u + j;

  float a0 = src[j];
  {
    const int ksq = b * 16;  // t = 0
    fbp[basea + (ksq >> 2) * 4096 + (ksq & 3) * 128] = (unsigned short)f2bf(a0);
  }
  float r = mul_rn_nofma(a0, a0);
  float s = fabsf(a0);
  for (int i = 8; i < 128; i += 8) {
    const float v = src[i + j];
    const int ksq = b * 16 + (i >> 3);
    fbp[basea + (ksq >> 2) * 4096 + (ksq & 3) * 128] = (unsigned short)f2bf(v);
    r = r + mul_rn_nofma(v, v);
    s = s + fabsf(v);
  }
  // exact numpy pairwise tree: ((r0+r1)+(r2+r3))+((r4+r5)+(r6+r7)), then blk0+blk1
  r = r + __shfl_xor(r, 1, 64);
  r = r + __shfl_xor(r, 2, 64);
  r = r + __shfl_xor(r, 4, 64);
  r = r + __shfl_xor(r, 8, 64);
  s = s + __shfl_xor(s, 1, 64);
  s = s + __shfl_xor(s, 2, 64);
  s = s + __shfl_xor(s, 4, 64);
  s = s + __shfl_xor(s, 8, 64);
  if ((l & 15) == 0) {
    if (isz) {
      ws[WS_ZNORM + row] = r;
      const float margin = 2.0e-6f * s + 4.0e-5f;
      ws[WS_MARGIN + row] = margin;
      ws[WS_CUT0 + row] = 3.10f * sqrtf(r) * 7.0467e-5f - margin;
      ((unsigned int*)ws)[WS_CNT + row] = 0u;
    } else {
      ws[WS_WNORM + (row - N_ROWS)] = r;
    }
  }
  if (blockIdx.x == 0 && tid == 0) {
    ws[WS_LOSS] = 0.0f;
    ((unsigned int*)ws)[WS_OVF] = 0u;
  }
}

// bf16 MFMA screen GEMM - NO LDS, NO BARRIERS, 64x64 wave tile (r7 champion)
// + EXPLICIT PING-PONG FRAGMENT PREFETCH.
// Theory (r9 post-mortem): r7 is latency-bound, not BW-bound (26 B/cyc/CU
// achieved vs ~56-64 available; MfmaUtil 22.6% = MFMA-floor/measured). The
// counters show WHY: VGPR_Count=64 - the compiler allocated only ONE fragment
// set, so each step serializes loads -> waitcnt -> MFMA. Fix: two static
// fragment banks (af/bg[2][4], parity indices static under full unroll),
// prefetch step ks+1 before the MFMA cluster of ks. ~150 regs/wave -> still
// 3 waves/SIMD (__launch_bounds__(256,3)); load latency hides under the
// 310-cyc MFMA window. Operand values and per-acc MFMA order (ks ascending)
// unchanged -> acc bits identical -> candidate set & margin proof intact.
// Tripwire: WRITE_SIZE must stay ~88 MB (no spill).
__global__ __launch_bounds__(256, 3) void gemm_screen_kernel(
    const unsigned short* __restrict__ zfrag, const unsigned short* __restrict__ wfrag,
    float* __restrict__ ws, uint2* __restrict__ candp) {
  const int tid = threadIdx.x;
  const int w = tid >> 6, l = tid & 63;
  const int lr = l & 15, lq = l >> 4;
  const int wr = (w >> 1) * 64, wc = (w & 1) * 64;
  const int rowBase = blockIdx.y * 128, colBase = blockIdx.x * 128;
  unsigned int* cntp = (unsigned int*)ws + WS_CNT;

  // fragment pointers, 16B units: flat = tile*4096 + ks*512 + sub*64 + l
  const bf16x8* za =
      (const bf16x8*)zfrag + ((size_t)blockIdx.y * 64 + (w >> 1) * 4) * 64 + l;
  const bf16x8* wa =
      (const bf16x8*)wfrag + ((size_t)blockIdx.x * 64 + (w & 1) * 4) * 64 + l;

  f32x4 acc[4][4];
#pragma unroll
  for (int mi = 0; mi < 4; ++mi)
#pragma unroll
    for (int ni = 0; ni < 4; ++ni) acc[mi][ni] = (f32x4){0.f, 0.f, 0.f, 0.f};

  bf16x8 af[2][4], bg[2][4];
#pragma unroll
  for (int mi = 0; mi < 4; ++mi) {
    af[0][mi] = za[mi * 64];
    bg[0][mi] = wa[mi * 64];
  }

#pragma unroll
  for (int ks = 0; ks < 8; ++ks) {
    const int c = ks & 1, n = c ^ 1;  // static after unroll (rule #20 safe)
    if (ks < 7) {
#pragma unroll
      for (int mi = 0; mi < 4; ++mi) {
        af[n][mi] = za[((ks + 1) * 8 + mi) * 64];
        bg[n][mi] = wa[((ks + 1) * 8 + mi) * 64];
      }
    }
#pragma unroll
    for (int mi = 0; mi < 4; ++mi)
#pragma unroll
      for (int ni = 0; ni < 4; ++ni)
        acc[mi][ni] =
            __builtin_amdgcn_mfma_f32_16x16x32_bf16(af[c][mi], bg[c][ni], acc[mi][ni], 0, 0, 0);
  }

  // Append-only epilogue (r5-proven): C/D layout col = lane&15,
  // row = (lane>>4)*4 + reg; cuts read as float4 straight from ws.
#pragma unroll
  for (int mi = 0; mi < 4; ++mi) {
    const float4 cutv = *(const float4*)(ws + WS_CUT0 + rowBase + wr + mi * 16 + lq * 4);
    const float cuta[4] = {cutv.x, cutv.y, cutv.z, cutv.w};
#pragma unroll
    for (int r = 0; r < 4; ++r) {
      const int lrow = wr + mi * 16 + lq * 4 + r;
      const float cut = cuta[r];
#pragma unroll
      for (int ni = 0; ni < 4; ++ni) {
        if (acc[mi][ni][r] >= cut) {
          const int grow = rowBase + lrow;
          const int gcol = colBase + wc + ni * 16 + lr;
          const unsigned int pos = atomicAdd(&cntp[grow], 1u);
          if (pos < CAP) {
            uint2 e;
            e.x = __float_as_uint(acc[mi][ni][r]);
            e.y = (unsigned int)gcol;
            candp[(size_t)grow * CAP + pos] = e;
          }
        }
      }
    }
  }
}

// One WAVE per row. Lanes 0..cv-1 load candidates coalesced; shuffle-reduce
// candmax; rigor gate unchanged. Survivors run the exact np dot_chain in
// parallel lanes; argmin via packed (dist_bits<<32 | k) key (dist ~ 256 > 0 ->
// uint order = float order; ties -> lowest k = np.argmin). Fallback rows get a
// -1 sentinel index; gather_loss resolves them from the u64 slots.
__global__ void recheck_kernel(const float* __restrict__ z, const float* __restrict__ W,
                               float* __restrict__ ws, const uint2* __restrict__ candp,
                               float* __restrict__ out) {
  const int lane = threadIdx.x & 63;
  const int row = blockIdx.x * 4 + (threadIdx.x >> 6);
  const unsigned int cv = ((const unsigned int*)ws)[WS_CNT + row];
  const float margin = ws[WS_MARGIN + row];
  const float cut0 = ws[WS_CUT0 + row];
  bool fb = (cv == 0u) || (cv > CAP);
  uint2 e;
  e.x = 0u; e.y = 0u;
  float av = -3.4e38f;
  if (!fb && lane < (int)cv) {
    e = candp[(size_t)row * CAP + lane];
    av = __uint_as_float(e.x);
  }
  float candmax = av;
#pragma unroll
  for (int s = 1; s < 64; s <<= 1) candmax = fmaxf(candmax, __shfl_xor(candmax, s, 64));
  if (!fb && candmax - margin < cut0) fb = true;  // cannot prove superset -> exact scan
  if (fb) {
    if (lane == 0) {
      ((unsigned long long*)((unsigned int*)ws + WS_SLOT))[row] = ~0ull;
      const unsigned int p = atomicAdd(&((unsigned int*)ws)[WS_OVF], 1u);
      ((unsigned int*)ws)[WS_OVFLIST + p] = (unsigned int)row;
      out[IDX_OFF + row] = -1.0f;  // sentinel: resolved by gather_loss
    }
    return;
  }
  const float fcut = candmax - margin;
  unsigned long long key = ~0ull;
  if (lane < (int)cv && av >= fcut) {  // below final cut: cannot be argmin
    const int k = (int)e.y;
    const float zn = ws[WS_ZNORM + row];
    const float m = dot_chain(z + (size_t)row * DIM, W + (size_t)k * DIM);
    const float dist = (zn + ws[WS_WNORM + k]) - 2.0f * m;
    key = ((unsigned long long)__float_as_uint(dist) << 32) | (unsigned int)k;
  }
#pragma unroll
  for (int s = 1; s < 64; s <<= 1) {
    const unsigned long long o = (unsigned long long)__shfl_xor((long long)key, s, 64);
    key = (o < key) ? o : key;
  }
  if (lane == 0) out[IDX_OFF + row] = (float)(unsigned int)(key & 0xffffffffull);
}

// Grid-parallel exact fallback: work item = (queued row, 256-code chunk). Each
// thread one code -> exact np dist; block-reduce min; u64 atomicMin combine.
__global__ void fallback_compute(const float* __restrict__ z, const float* __restrict__ W,
                                 float* __restrict__ ws) {
  __shared__ unsigned long long part[4];
  const unsigned int n = ((const unsigned int*)ws)[WS_OVF];
  unsigned long long* slots = (unsigned long long*)((unsigned int*)ws + WS_SLOT);
  const unsigned int total = n * 32u;
  for (unsigned int item = blockIdx.x; item < total; item += gridDim.x) {
    const int row = (int)((const unsigned int*)ws)[WS_OVFLIST + (item >> 5)];
    const int k = (int)(item & 31u) * 256 + threadIdx.x;
    const float zn = ws[WS_ZNORM + row];
    const float m = dot_chain(z + (size_t)row * DIM, W + (size_t)k * DIM);
    const float dist = (zn + ws[WS_WNORM + k]) - 2.0f * m;
    unsigned long long key =
        ((unsigned long long)__float_as_uint(dist) << 32) | (unsigned int)k;
#pragma unroll
    for (int s = 1; s < 64; s <<= 1) {
      const unsigned long long o = __shfl_xor((long long)key, s, 64);
      key = (o < key) ? o : key;
    }
    if ((threadIdx.x & 63) == 0) part[threadIdx.x >> 6] = key;
    __syncthreads();
    if (threadIdx.x == 0) {
      unsigned long long b = part[0];
      b = (part[1] < b) ? part[1] : b;
      b = (part[2] < b) ? part[2] : b;
      b = (part[3] < b) ? part[3] : b;
      atomicMin(&slots[row], b);
    }
    __syncthreads();
  }
}

// 64 rows/block: gather W[idx], quantized_st = z + (q - z), loss partial sums.
// Rows with the -1 sentinel read their exact-fallback result from the u64 slot.
__global__ void gather_loss_kernel(const float* __restrict__ z, const float* __restrict__ W,
                                   float* __restrict__ out, float* __restrict__ ws) {
  const int tid = threadIdx.x;
  const int rowBase = blockIdx.x * 64;
  float lsum = 0.0f;
  for (int p = 0; p < 16; ++p) {
    const int row = rowBase + p * 4 + (tid >> 6);
    const int c4 = tid & 63;
    int idx = (int)out[IDX_OFF + row];
    if (idx < 0) {
      const unsigned long long key =
          ((const unsigned long long*)((const unsigned int*)ws + WS_SLOT))[row];
      idx = (int)(unsigned int)(key & 0xffffffffull);
      out[IDX_OFF + row] = (float)idx;  // all 64 threads write same value: benign
    }
    const float4 zv = *(const float4*)(z + (size_t)row * DIM + c4 * 4);
    const float4 qv = *(const float4*)(W + (size_t)idx * DIM + c4 * 4);
    float4 t, o;
    t.x = qv.x - zv.x; t.y = qv.y - zv.y; t.z = qv.z - zv.z; t.w = qv.w - zv.w;
    o.x = zv.x + t.x;  o.y = zv.y + t.y;  o.z = zv.z + t.z;  o.w = zv.w + t.w;
    *(float4*)(out + (size_t)row * DIM + c4 * 4) = o;
    lsum += t.x * t.x + t.y * t.y + t.z * t.z + t.w * t.w;
  }
#pragma unroll
  for (int m = 1; m < 64; m <<= 1) lsum += __shfl_xor(lsum, m, 64);
  __shared__ float part[4];
  if ((tid & 63) == 0) part[tid >> 6] = lsum;
  __syncthreads();
  if (tid == 0) atomicAdd(&ws[WS_LOSS], (part[0] + part[1]) + (part[2] + part[3]));
}

__global__ void finalize_kernel(const float* __restrict__ ws, float* __restrict__ out) {
  if (threadIdx.x == 0 && blockIdx.x == 0) {
    const float mean = ws[WS_LOSS] / (float)(N_ROWS * DIM);
    out[LOSS_OFF] = mean + 0.25f * mean;
  }
}

extern "C" void kernel_launch(void* const* d_in, const int* in_sizes, int n_in,
                              void* d_out, int out_size, void* d_ws, size_t ws_size,
                              hipStream_t stream) {
  (void)in_sizes; (void)n_in; (void)out_size; (void)ws_size;
  const float* z = (const float*)d_in[0];
  const float* W = (const float*)d_in[1];
  float* out = (float*)d_out;
  float* ws = (float*)d_ws;
  unsigned short* outu = (unsigned short*)d_out;
  const unsigned short* wfrag = outu + OUT_WBF_U16;
  const unsigned short* zfrag = outu + OUT_ZBF_U16;
  uint2* candp = (uint2*)((float*)d_out + OUT_CAND_F);

  hipLaunchKernelGGL(prep_kernel, dim3((N_ROWS + K_CODES) / 16), dim3(256), 0, stream,
                     z, W, ws, outu);
  hipLaunchKernelGGL(gemm_screen_kernel, dim3(K_CODES / 128, N_ROWS / 128), dim3(256),
                     0, stream, zfrag, wfrag, ws, candp);
  hipLaunchKernelGGL(recheck_kernel, dim3(N_ROWS / 4), dim3(256), 0, stream,
                     z, W, ws, candp, out);
  hipLaunchKernelGGL(fallback_compute, dim3(2048), dim3(256), 0, stream, z, W, ws);
  hipLaunchKernelGGL(gather_loss_kernel, dim3(N_ROWS / 64), dim3(256), 0, stream,
                     z, W, out, ws);
  hipLaunchKernelGGL(finalize_kernel, dim3(1), dim3(64), 0, stream, ws, out);
}